// Round 4
// baseline (174.834 us; speedup 1.0000x reference)
//
#include <hip/hip_runtime.h>

#define HH 384
#define WW 384
#define HWP (HH * WW)   // 147456
#define DD 64
#define BB 2
#define NG 16           // 16 groups of 4 channels

// ============ Fast path: packed float4 layout, cache-tap stencil ============

// K1: per-pixel stats + repack channels into float4 groups G[b][g][y][x]
__global__ __launch_bounds__(256) void stats_pack_k(const float* __restrict__ des,
                                                    float4* __restrict__ G,
                                                    float* __restrict__ ssq,
                                                    float* __restrict__ smm) {
    int idx = blockIdx.x * 256 + threadIdx.x;        // 0 .. 294911
    int b = idx / HWP;
    int p = idx - b * HWP;
    const float* base = des + (size_t)b * DD * HWP + p;
    float4* gb = G + (size_t)b * NG * HWP + p;
    float ss = 0.f, s0 = 0.f;
#pragma unroll 4
    for (int g = 0; g < NG; ++g) {
        float4 v;
        v.x = base[(size_t)(4 * g + 0) * HWP];
        v.y = base[(size_t)(4 * g + 1) * HWP];
        v.z = base[(size_t)(4 * g + 2) * HWP];
        v.w = base[(size_t)(4 * g + 3) * HWP];
        ss = fmaf(v.x, v.x, ss); ss = fmaf(v.y, v.y, ss);
        ss = fmaf(v.z, v.z, ss); ss = fmaf(v.w, v.w, ss);
        s0 += v.x + v.y + v.z + v.w;
        gb[(size_t)g * HWP] = v;
    }
    ssq[idx] = ss;
    smm[idx] = s0;
}

// K2: dilated 5x5 dot stencil, taps straight from L1/L2 on packed layout.
// 2 px/thread (y, y+4), no LDS, no barriers.
__global__ __launch_bounds__(256, 3) void ssd_cache_k(const float4* __restrict__ G,
                                                      const float* __restrict__ ssq,
                                                      const float* __restrict__ smm,
                                                      float* __restrict__ out) {
    const int tx = threadIdx.x;            // 0..63
    const int ty = threadIdx.y;            // 0..3

    // XCD-aware bijective swizzle (576 = 8 * 72): each XCD gets a y-stripe
    int bid = blockIdx.x;
    int swz = (bid & 7) * 72 + (bid >> 3);
    int b  = swz / (6 * 48);
    int r0 = swz % (6 * 48);
    int by = r0 / 6;
    int bx = r0 - by * 6;
    const int x = bx * 64 + tx;
    const int y = by * 8 + ty;             // px A; px B = y+4

    int roff[6], coff[5];
#pragma unroll
    for (int m = 0; m < 6; ++m) {
        int yy = y - 8 + 4 * m; yy = yy < 0 ? 0 : (yy > HH - 1 ? HH - 1 : yy);
        roff[m] = yy * WW;
    }
#pragma unroll
    for (int j = 0; j < 5; ++j) {
        int xx = x - 8 + 4 * j; xx = xx < 0 ? 0 : (xx > WW - 1 ? WW - 1 : xx);
        coff[j] = xx;
    }

    float accA[25], accB[25];
#pragma unroll
    for (int n = 0; n < 25; ++n) { accA[n] = 0.f; accB[n] = 0.f; }

    const float4* Gb = G + (size_t)b * NG * HWP;
#pragma unroll 1
    for (int g = 0; g < NG; ++g) {
        const float4* p = Gb + (size_t)g * HWP;
        float4 v[6][5];
#pragma unroll
        for (int m = 0; m < 6; ++m)
#pragma unroll
            for (int j = 0; j < 5; ++j)
                v[m][j] = p[roff[m] + coff[j]];
        float4 cA = v[2][2];
        float4 cB = v[3][2];
#pragma unroll
        for (int m = 0; m < 5; ++m)
#pragma unroll
            for (int j = 0; j < 5; ++j) {
                int n = m * 5 + j;
                accA[n] = fmaf(cA.x, v[m][j].x, accA[n]);
                accA[n] = fmaf(cA.y, v[m][j].y, accA[n]);
                accA[n] = fmaf(cA.z, v[m][j].z, accA[n]);
                accA[n] = fmaf(cA.w, v[m][j].w, accA[n]);
                accB[n] = fmaf(cB.x, v[m + 1][j].x, accB[n]);
                accB[n] = fmaf(cB.y, v[m + 1][j].y, accB[n]);
                accB[n] = fmaf(cB.z, v[m + 1][j].z, accB[n]);
                accB[n] = fmaf(cB.w, v[m + 1][j].w, accB[n]);
            }
    }

    // epilogue: ssq taps from cache
    const float* sp = ssq + (size_t)b * HWP;
    float sv[6][5];
#pragma unroll
    for (int m = 0; m < 6; ++m)
#pragma unroll
        for (int j = 0; j < 5; ++j)
            sv[m][j] = sp[roff[m] + coff[j]];

#pragma unroll
    for (int a = 0; a < 2; ++a) {
        int py = y + 4 * a;
        float* acc = a ? accB : accA;
        float ssA = sv[2 + a][2];
        float mu = smm[(size_t)b * HWP + py * WW + x] * (1.0f / 64);
        float var = ssA * (1.0f / 64) - mu * mu;
        float sabs = sqrtf(fmaxf(var, 0.f));
        float L = 0.f;
#pragma unroll
        for (int m = 0; m < 5; ++m)
#pragma unroll
            for (int j = 0; j < 5; ++j) {
                float ssB = sv[m + a][j];
                float d2 = fmaxf(ssA + ssB - 2.f * acc[m * 5 + j], 0.f);
                L += sqrtf(d2);
            }
        float srel = L * (1.0f / 25);
        float sraw = sabs * srel;
        out[(size_t)b * HWP + py * WW + x] = sraw / (sraw + 1.f);
    }
}

// ============ Fallback path (R3): LDS-staged, in case ws is small ============

__global__ __launch_bounds__(256) void stats_k(const float* __restrict__ des,
                                               float* __restrict__ ssq,
                                               float* __restrict__ smm) {
    int idx = blockIdx.x * 256 + threadIdx.x;
    int b = idx / HWP;
    int p = idx - b * HWP;
    const float* base = des + (size_t)b * DD * HWP + p;
    float ss = 0.f, s0 = 0.f;
#pragma unroll 8
    for (int d = 0; d < DD; ++d) {
        float v = base[(size_t)d * HWP];
        ss = fmaf(v, v, ss);
        s0 += v;
    }
    ssq[idx] = ss;
    smm[idx] = s0;
}

#define TX 64
#define TY 8
#define LR 24
#define LC 80
#define LN (LR * LC)
#define NWG 576

__global__ __launch_bounds__(256) void ssd_lds_k(const float* __restrict__ des,
                                                 const float* __restrict__ ssq,
                                                 const float* __restrict__ smm,
                                                 float* __restrict__ out) {
    __shared__ float4 lds[2][LN];
    const int tx = threadIdx.x, ty = threadIdx.y;
    const int tid = ty * 64 + tx;
    int bid = blockIdx.x;
    int swz = (bid & 7) * (NWG / 8) + (bid >> 3);
    int b  = swz / (6 * 48);
    int r0 = swz % (6 * 48);
    int by = r0 / 6, bx = r0 - by * 6;
    const int x0 = bx * TX, y0 = by * TY;
    int goff[8];
#pragma unroll
    for (int k = 0; k < 8; ++k) {
        int i = tid + 256 * k;
        if (i < LN) {
            int r = i / LC, c = i - (i / LC) * LC;
            int gy = y0 + r - 8; gy = gy < 0 ? 0 : (gy > HH - 1 ? HH - 1 : gy);
            int gx = x0 + c - 8; gx = gx < 0 ? 0 : (gx > WW - 1 ? WW - 1 : gx);
            goff[k] = gy * WW + gx;
        } else goff[k] = 0;
    }
    const float* dp = des + (size_t)b * DD * HWP;
    float4 rg[8];
    auto LOADG = [&](int g) {
        const float* p = dp + (size_t)(4 * g) * HWP;
#pragma unroll
        for (int k = 0; k < 8; ++k) {
            rg[k].x = p[goff[k]]; rg[k].y = p[goff[k] + HWP];
            rg[k].z = p[goff[k] + 2 * HWP]; rg[k].w = p[goff[k] + 3 * HWP];
        }
    };
    auto WRITE = [&](int bb) {
#pragma unroll
        for (int k = 0; k < 7; ++k) lds[bb][tid + 256 * k] = rg[k];
        if (tid < LN - 1792) lds[bb][tid + 1792] = rg[7];
    };
    float acc0[25], acc1[25];
#pragma unroll
    for (int n = 0; n < 25; ++n) { acc0[n] = 0.f; acc1[n] = 0.f; }
    auto COMPUTE = [&](int bb) {
        const float4* L = lds[bb];
        const int base = ty * LC + tx;
        float4 c0 = L[base + 8 * LC + 8];
        float4 c1 = L[base + 12 * LC + 8];
#pragma unroll
        for (int m = 0; m < 6; ++m)
#pragma unroll
            for (int j = 0; j < 5; ++j) {
                float4 v = L[base + (4 * m) * LC + 4 * j];
                if (m < 5) {
                    int n = m * 5 + j;
                    acc0[n] = fmaf(c0.x, v.x, acc0[n]); acc0[n] = fmaf(c0.y, v.y, acc0[n]);
                    acc0[n] = fmaf(c0.z, v.z, acc0[n]); acc0[n] = fmaf(c0.w, v.w, acc0[n]);
                }
                if (m >= 1) {
                    int n = (m - 1) * 5 + j;
                    acc1[n] = fmaf(c1.x, v.x, acc1[n]); acc1[n] = fmaf(c1.y, v.y, acc1[n]);
                    acc1[n] = fmaf(c1.z, v.z, acc1[n]); acc1[n] = fmaf(c1.w, v.w, acc1[n]);
                }
            }
    };
    LOADG(0); WRITE(0); __syncthreads();
    for (int g = 0; g < 16; g += 2) {
        LOADG(g + 1); COMPUTE(0); WRITE(1); __syncthreads();
        if (g + 2 < 16) LOADG(g + 2);
        COMPUTE(1);
        if (g + 2 < 16) WRITE(0);
        __syncthreads();
    }
    float* lf = (float*)&lds[0][0];
    const float* sp = ssq + (size_t)b * HWP;
    {
        float r[8];
#pragma unroll
        for (int k = 0; k < 8; ++k) r[k] = sp[goff[k]];
#pragma unroll
        for (int k = 0; k < 7; ++k) lf[tid + 256 * k] = r[k];
        if (tid < LN - 1792) lf[tid + 1792] = r[7];
    }
    __syncthreads();
    float sv[6][5];
#pragma unroll
    for (int m = 0; m < 6; ++m)
#pragma unroll
        for (int j = 0; j < 5; ++j)
            sv[m][j] = lf[(ty + 4 * m) * LC + tx + 4 * j];
#pragma unroll
    for (int a = 0; a < 2; ++a) {
        int py = ty + 4 * a;
        float* acc = a ? acc1 : acc0;
        float ssA = sv[2 + a][2];
        float mu = smm[(size_t)b * HWP + (y0 + py) * WW + x0 + tx] * (1.0f / 64);
        float var = ssA * (1.0f / 64) - mu * mu;
        float sabs = sqrtf(fmaxf(var, 0.f));
        float L = 0.f;
#pragma unroll
        for (int m = 0; m < 5; ++m)
#pragma unroll
            for (int j = 0; j < 5; ++j) {
                float ssB = sv[m + a][j];
                float d2 = fmaxf(ssA + ssB - 2.f * acc[m * 5 + j], 0.f);
                L += sqrtf(d2);
            }
        float srel = L * (1.0f / 25);
        float sraw = sabs * srel;
        out[(size_t)b * HWP + (y0 + py) * WW + x0 + tx] = sraw / (sraw + 1.f);
    }
}

extern "C" void kernel_launch(void* const* d_in, const int* in_sizes, int n_in,
                              void* d_out, int out_size, void* d_ws, size_t ws_size,
                              hipStream_t stream) {
    const float* des = (const float*)d_in[0];
    float* out = (float*)d_out;

    const size_t gElems = (size_t)BB * NG * HWP;         // float4 elements
    const size_t needBytes = gElems * 16 + (size_t)BB * HWP * 2 * 4;

    if (ws_size >= needBytes) {
        float4* G = (float4*)d_ws;
        float* ssq = (float*)d_ws + gElems * 4;
        float* smm = ssq + (size_t)BB * HWP;
        stats_pack_k<<<dim3((BB * HWP) / 256), dim3(256), 0, stream>>>(des, G, ssq, smm);
        ssd_cache_k<<<dim3(576), dim3(64, 4), 0, stream>>>(G, ssq, smm, out);
    } else {
        float* ssq = (float*)d_ws;
        float* smm = ssq + (size_t)BB * HWP;
        stats_k<<<dim3((BB * HWP) / 256), dim3(256), 0, stream>>>(des, ssq, smm);
        ssd_lds_k<<<dim3(NWG), dim3(64, 4), 0, stream>>>(des, ssq, smm, out);
    }
}

// Round 6
// 91.042 us; speedup vs baseline: 1.9204x; 1.9204x over previous
//
#include <hip/hip_runtime.h>

#define HH 384
#define WW 384
#define HWP (HH * WW)   // 147456
#define DD 64
#define BB 2
#define NG 16           // 16 groups of 4 channels

#define TX 64
#define TY 8
#define LR 24           // TY + 16 halo rows
#define LC 80           // TX + 16 halo cols
#define LN (LR * LC)    // 1920 slots
#define NWG 576         // 6 * 48 * 2 = 8 XCD * 72

typedef __fp16 h2 __attribute__((ext_vector_type(2)));
union h4 { uint2 u; h2 h[2]; };

#if __has_builtin(__builtin_amdgcn_fdot2)
#define DOT4(acc, a, b)                                         \
    acc = __builtin_amdgcn_fdot2((a).h[0], (b).h[0], acc, false); \
    acc = __builtin_amdgcn_fdot2((a).h[1], (b).h[1], acc, false)
#else
#define DOT4(acc, a, b)                                   \
    acc = fmaf((float)(a).h[0].x, (float)(b).h[0].x, acc); \
    acc = fmaf((float)(a).h[0].y, (float)(b).h[0].y, acc); \
    acc = fmaf((float)(a).h[1].x, (float)(b).h[1].x, acc); \
    acc = fmaf((float)(a).h[1].y, (float)(b).h[1].y, acc)
#endif

// Fused: stats + dilated 5x5 dot stencil. f16 LDS staging (channel groups of
// 4), double-buffered, load-early/write-late. 2 px/thread (y, y+4).
__global__ __launch_bounds__(256) void fused_k(const float* __restrict__ des,
                                               float* __restrict__ out) {
    __shared__ h4 lds[2][LN];   // 30,720 B
    const int tx = threadIdx.x;            // 0..63
    const int ty = threadIdx.y;            // 0..3
    const int tid = ty * 64 + tx;

    // XCD-aware bijective swizzle (576 = 8 * 72)
    int bid = blockIdx.x;
    int swz = (bid & 7) * 72 + (bid >> 3);
    int b  = swz / (6 * 48);
    int r0 = swz % (6 * 48);
    int by = r0 / 6;
    int bx = r0 - by * 6;
    const int x0 = bx * TX, y0 = by * TY;
    const int x = x0 + tx;
    const int y = y0 + ty;                 // px A; px B = y+4

    // Clamped global offsets for this thread's 8 staging slots
    int goff[8];
#pragma unroll
    for (int k = 0; k < 8; ++k) {
        int i = tid + 256 * k;
        if (i < LN) {
            int r = i / LC, c = i - (i / LC) * LC;
            int gy = y0 + r - 8; gy = gy < 0 ? 0 : (gy > HH - 1 ? HH - 1 : gy);
            int gx = x0 + c - 8; gx = gx < 0 ? 0 : (gx > WW - 1 ? WW - 1 : gx);
            goff[k] = gy * WW + gx;
        } else {
            goff[k] = 0;
        }
    }

    const float* dp = des + (size_t)b * DD * HWP;
    float4 rg[8];
    float ss[8], sm[8];
#pragma unroll
    for (int k = 0; k < 8; ++k) { ss[k] = 0.f; sm[k] = 0.f; }

    auto ISSUE = [&](int g) {   // issue global loads for channels 4g..4g+3
        const float* p = dp + (size_t)(4 * g) * HWP;
#pragma unroll
        for (int k = 0; k < 8; ++k) {
            rg[k].x = p[goff[k]];
            rg[k].y = p[goff[k] + HWP];
            rg[k].z = p[goff[k] + 2 * HWP];
            rg[k].w = p[goff[k] + 3 * HWP];
        }
    };
    auto FIN = [&](int bb) {    // stats acc + cvt + LDS write
#pragma unroll
        for (int k = 0; k < 8; ++k) {
            float4 v = rg[k];
            ss[k] = fmaf(v.x, v.x, ss[k]); ss[k] = fmaf(v.y, v.y, ss[k]);
            ss[k] = fmaf(v.z, v.z, ss[k]); ss[k] = fmaf(v.w, v.w, ss[k]);
            sm[k] += (v.x + v.y) + (v.z + v.w);
            h4 h;
            h.h[0] = __builtin_amdgcn_cvt_pkrtz(v.x, v.y);
            h.h[1] = __builtin_amdgcn_cvt_pkrtz(v.z, v.w);
            if (k < 7 || tid < LN - 1792) lds[bb][tid + 256 * k] = h;
        }
    };

    float accA[25], accB[25];
#pragma unroll
    for (int n = 0; n < 25; ++n) { accA[n] = 0.f; accB[n] = 0.f; }

    const int base = ty * LC + tx;
    auto COMPUTE = [&](int bb) {
        const h4* L = lds[bb];
        h4 c0 = L[base + 8 * LC + 8];    // center px A (m=2,j=2)
        h4 c1 = L[base + 12 * LC + 8];   // center px B (m=3,j=2)
#pragma unroll
        for (int m = 0; m < 6; ++m)
#pragma unroll
            for (int j = 0; j < 5; ++j) {
                h4 v = L[base + (4 * m) * LC + 4 * j];
                if (m < 5)  { DOT4(accA[m * 5 + j], c0, v); }
                if (m >= 1) { DOT4(accB[(m - 1) * 5 + j], c1, v); }
            }
    };

    // pipeline: ISSUE(g+1) | COMPUTE(g) | FIN(g+1) | barrier
    ISSUE(0);
    FIN(0);
    __syncthreads();
    for (int g = 0; g < NG; g += 2) {
        ISSUE(g + 1);
        COMPUTE(0);
        FIN(1);
        __syncthreads();
        if (g + 2 < NG) ISSUE(g + 2);
        COMPUTE(1);
        if (g + 2 < NG) FIN(0);
        __syncthreads();
    }

    // epilogue: write per-slot stats planes into LDS (reuse buffers)
    float* ssp = (float*)&lds[0][0];   // 1920 floats
    float* smp = (float*)&lds[1][0];   // 1920 floats
#pragma unroll
    for (int k = 0; k < 8; ++k) {
        if (k < 7 || tid < LN - 1792) {
            ssp[tid + 256 * k] = ss[k];
            smp[tid + 256 * k] = sm[k];
        }
    }
    __syncthreads();

    float sv[6][5];
#pragma unroll
    for (int m = 0; m < 6; ++m)
#pragma unroll
        for (int j = 0; j < 5; ++j)
            sv[m][j] = ssp[base + (4 * m) * LC + 4 * j];

    // clamped tap coordinates (for exact-zero self/duplicate taps)
    int yc[6], xc[5];
#pragma unroll
    for (int m = 0; m < 6; ++m) {
        int yy = y - 8 + 4 * m; yc[m] = yy < 0 ? 0 : (yy > HH - 1 ? HH - 1 : yy);
    }
#pragma unroll
    for (int j = 0; j < 5; ++j) {
        int xx = x - 8 + 4 * j; xc[j] = xx < 0 ? 0 : (xx > WW - 1 ? WW - 1 : xx);
    }

#pragma unroll
    for (int a = 0; a < 2; ++a) {
        const int py = y + 4 * a;
        const float* acc = a ? accB : accA;
        float ssA = sv[2 + a][2];
        float mu = smp[base + (8 + 4 * a) * LC + 8] * (1.0f / 64);
        float var = ssA * (1.0f / 64) - mu * mu;
        float sabs = sqrtf(fmaxf(var, 0.f));
        float L = 0.f;
#pragma unroll
        for (int m = 0; m < 5; ++m)
#pragma unroll
            for (int j = 0; j < 5; ++j) {
                float ssB = sv[m + a][j];
                float d2 = fmaxf(ssA + ssB - 2.f * acc[m * 5 + j], 0.f);
                float sq = sqrtf(d2);
                // taps that clamp onto the center pixel are exactly 0 in ref
                L += (yc[m + a] == py && xc[j] == x) ? 0.f : sq;
            }
        float srel = L * (1.0f / 25);
        float sraw = sabs * srel;
        out[(size_t)b * HWP + py * WW + x] = sraw / (sraw + 1.f);
    }
}

extern "C" void kernel_launch(void* const* d_in, const int* in_sizes, int n_in,
                              void* d_out, int out_size, void* d_ws, size_t ws_size,
                              hipStream_t stream) {
    const float* des = (const float*)d_in[0];
    float* out = (float*)d_out;
    fused_k<<<dim3(NWG), dim3(64, 4), 0, stream>>>(des, out);
}